// Round 5
// baseline (1047.458 us; speedup 1.0000x reference)
//
#include <hip/hip_runtime.h>
#include <cstdint>
#include <cstddef>

// Problem constants
#define N_ROWS  16384      // 4*4096 tokens
#define D_MOD   1024
#define D_LAT   4096
#define K_TOP   16

typedef _Float16 f16_t;
typedef _Float16 half8 __attribute__((ext_vector_type(8)));
typedef float f32x4 __attribute__((ext_vector_type(4)));

// ---------------------------------------------------------------------------
// global_load_lds helper (16B per lane, LDS dest = wave-uniform base + lane*16)
// ---------------------------------------------------------------------------
__device__ __forceinline__ void gload_lds16(const void* g, void* l) {
    __builtin_amdgcn_global_load_lds(
        (const __attribute__((address_space(1))) void*)g,
        (__attribute__((address_space(3))) void*)l, 16, 0, 0);
}

// ---------------------------------------------------------------------------
// Kernel: split fp32 -> fp16 hi + fp16 lo*2^11  (exact Fast2Sum residual)
// ---------------------------------------------------------------------------
__global__ __launch_bounds__(256) void split_f16(
    const float* __restrict__ src, f16_t* __restrict__ hi,
    f16_t* __restrict__ lo, int n4)
{
    const int i = blockIdx.x * 256 + threadIdx.x;
    if (i >= n4) return;
    const float4 v = ((const float4*)src)[i];
    union { f16_t h[4]; ushort4 u; } ph, pl;
    ph.h[0] = (f16_t)v.x; ph.h[1] = (f16_t)v.y;
    ph.h[2] = (f16_t)v.z; ph.h[3] = (f16_t)v.w;
    pl.h[0] = (f16_t)((v.x - (float)ph.h[0]) * 2048.0f);
    pl.h[1] = (f16_t)((v.y - (float)ph.h[1]) * 2048.0f);
    pl.h[2] = (f16_t)((v.z - (float)ph.h[2]) * 2048.0f);
    pl.h[3] = (f16_t)((v.w - (float)ph.h[3]) * 2048.0f);
    ((ushort4*)hi)[i] = ph.u;
    ((ushort4*)lo)[i] = pl.u;
}

// ---------------------------------------------------------------------------
// Kernel: transpose dec_w [1024][4096] -> decT [4096][1024]
// ---------------------------------------------------------------------------
__global__ __launch_bounds__(256) void transpose_dec(
    const float* __restrict__ DW, float* __restrict__ DT)
{
    __shared__ float tile[32][33];
    const int l0 = blockIdx.x * 32;
    const int d0 = blockIdx.y * 32;
    const int tx = threadIdx.x & 31;
    const int ty = threadIdx.x >> 5;
    #pragma unroll
    for (int i = 0; i < 32; i += 8)
        tile[ty + i][tx] = DW[(size_t)(d0 + ty + i) * D_LAT + l0 + tx];
    __syncthreads();
    #pragma unroll
    for (int i = 0; i < 32; i += 8)
        DT[(size_t)(l0 + ty + i) * D_MOD + d0 + tx] = tile[tx][ty + i];
}

// ---------------------------------------------------------------------------
// Fused MFMA GEMM at BK=32: pre = xh*wh + (xh*wl + xl*wh)/2048 + bias.
// 128x128 tile, 4 waves (2x2), each wave 64x64 (4x4 frags of 16x16x32).
// 4 LDS tiles (AH/AL/BH/BL) of [128 rows][32 k] f16 = 8KB each -> 32KB total
// (same LDS as round-2 3-pass; 1.5x MFMA-per-barrier, 2/3 staging traffic).
// Swizzle: 16B-chunk' = chunk ^ ((row>>1)&3) -> conflict-free b128 batches.
// Applied via pre-swizzled GLOBAL source + linear LDS dest (rule #21).
// ---------------------------------------------------------------------------
__global__ __launch_bounds__(256) void enc_gemm_f16(
    const f16_t* __restrict__ XH, const f16_t* __restrict__ XL,
    const f16_t* __restrict__ WH, const f16_t* __restrict__ WL,
    const float* __restrict__ B1, const float* __restrict__ B2,
    float* __restrict__ PRE)
{
    __shared__ char smem[32768];
    char* AsH = smem;
    char* AsL = smem + 8192;
    char* BsH = smem + 16384;
    char* BsL = smem + 24576;

    const int tid = threadIdx.x;
    const int w = tid >> 6;
    const int l = tid & 63;

    // XCD-bijective swizzle (4096 blocks % 8 == 0)
    const int bid = blockIdx.x;
    const int swz = (bid & 7) * 512 + (bid >> 3);
    const int bx = swz & 31;          // 32 n-blocks
    const int by = swz >> 5;          // 128 m-blocks
    const int m0 = by * 128, n0 = bx * 128;
    const int wm = w >> 1, wn = w & 1;

    f32x4 acc1[4][4], acc2[4][4];
    #pragma unroll
    for (int i = 0; i < 4; ++i)
        #pragma unroll
        for (int j = 0; j < 4; ++j) {
            acc1[i][j] = (f32x4)(0.0f);
            acc2[i][j] = (f32x4)(0.0f);
        }

    // staging geometry: slab = 16 rows (1KB); wave w covers slabs w and w+4
    // lane l -> row-in-slab l>>2, chunk-pos l&3; global k-chunk pre-swizzled:
    const int q = l >> 2;                               // row within slab
    const int gc = (l & 3) ^ ((l >> 3) & 3);            // source k-chunk
    // MFMA-read swizzled chunk (uniform over mi/ni since base%4 rows == 0)
    const int rc = (l >> 4) ^ ((l >> 1) & 3);
    const int fr = l & 15;

    const size_t abase = (size_t)m0 * D_MOD;
    const size_t bbase = (size_t)n0 * D_MOD;

    for (int k0 = 0; k0 < D_MOD; k0 += 32) {
        __syncthreads();   // all waves done reading LDS from previous step
        #pragma unroll
        for (int i = 0; i < 2; ++i) {
            const int slab = i * 4 + w;                 // 0..7
            const int rt = slab * 16 + q;               // tile row 0..127
            const size_t goff = (size_t)rt * D_MOD + k0 + gc * 8;
            const int ldst = slab * 1024;
            gload_lds16(XH + abase + goff, AsH + ldst);
            gload_lds16(XL + abase + goff, AsL + ldst);
            gload_lds16(WH + bbase + goff, BsH + ldst);
            gload_lds16(WL + bbase + goff, BsL + ldst);
        }
        __syncthreads();   // vmcnt(0) drained by compiler before barrier

        half8 ah[4], bh[4], bl[4], al[4];
        #pragma unroll
        for (int mi = 0; mi < 4; ++mi) {
            const int row = wm * 64 + mi * 16 + fr;
            ah[mi] = *(const half8*)(AsH + row * 64 + rc * 16);
        }
        #pragma unroll
        for (int ni = 0; ni < 4; ++ni) {
            const int col = wn * 64 + ni * 16 + fr;
            bh[ni] = *(const half8*)(BsH + col * 64 + rc * 16);
        }
        #pragma unroll
        for (int mi = 0; mi < 4; ++mi)
            #pragma unroll
            for (int ni = 0; ni < 4; ++ni)
                acc1[mi][ni] = __builtin_amdgcn_mfma_f32_16x16x32_f16(
                    ah[mi], bh[ni], acc1[mi][ni], 0, 0, 0);
        #pragma unroll
        for (int ni = 0; ni < 4; ++ni) {
            const int col = wn * 64 + ni * 16 + fr;
            bl[ni] = *(const half8*)(BsL + col * 64 + rc * 16);
        }
        #pragma unroll
        for (int mi = 0; mi < 4; ++mi)
            #pragma unroll
            for (int ni = 0; ni < 4; ++ni)
                acc2[mi][ni] = __builtin_amdgcn_mfma_f32_16x16x32_f16(
                    ah[mi], bl[ni], acc2[mi][ni], 0, 0, 0);
        #pragma unroll
        for (int mi = 0; mi < 4; ++mi) {
            const int row = wm * 64 + mi * 16 + fr;
            al[mi] = *(const half8*)(AsL + row * 64 + rc * 16);
        }
        #pragma unroll
        for (int mi = 0; mi < 4; ++mi)
            #pragma unroll
            for (int ni = 0; ni < 4; ++ni)
                acc2[mi][ni] = __builtin_amdgcn_mfma_f32_16x16x32_f16(
                    al[mi], bh[ni], acc2[mi][ni], 0, 0, 0);
    }

    // epilogue: pre = acc1 + acc2/2048 + bias
    const int lrow = (l >> 4) * 4;
    const int lcol = l & 15;
    #pragma unroll
    for (int ni = 0; ni < 4; ++ni) {
        const int col = n0 + wn * 64 + ni * 16 + lcol;
        const float bias = B1[col] + B2[col];
        #pragma unroll
        for (int mi = 0; mi < 4; ++mi) {
            const int row = m0 + wm * 64 + mi * 16 + lrow;
            #pragma unroll
            for (int j = 0; j < 4; ++j)
                PRE[(size_t)(row + j) * D_LAT + col] =
                    acc1[mi][ni][j] + acc2[mi][ni][j] * (1.0f / 2048.0f) + bias;
        }
    }
}

// ---------------------------------------------------------------------------
// Fallback: fp32 VALU GEMM (round-1, known-good)
// ---------------------------------------------------------------------------
__global__ __launch_bounds__(256) void enc_gemm_f32(
    const float* __restrict__ X, const float* __restrict__ W,
    const float* __restrict__ B1, const float* __restrict__ B2,
    float* __restrict__ PRE)
{
    __shared__ float Asm[16][128];
    __shared__ float Bsm[16][128];
    const int tid = threadIdx.x;
    const int m0 = blockIdx.y * 128;
    const int n0 = blockIdx.x * 128;
    const int tx = tid & 15;
    const int ty = tid >> 4;
    const int lr = tid >> 2;
    const int lk = (tid & 3) << 2;

    float acc[8][8];
    #pragma unroll
    for (int i = 0; i < 8; ++i)
        #pragma unroll
        for (int j = 0; j < 8; ++j) acc[i][j] = 0.f;

    const float* xp0 = X + (size_t)(m0 + lr) * D_MOD + lk;
    const float* xp1 = X + (size_t)(m0 + lr + 64) * D_MOD + lk;
    const float* wp0 = W + (size_t)(n0 + lr) * D_MOD + lk;
    const float* wp1 = W + (size_t)(n0 + lr + 64) * D_MOD + lk;

    for (int k0 = 0; k0 < D_MOD; k0 += 16) {
        const float4 a0 = *(const float4*)(xp0 + k0);
        const float4 a1 = *(const float4*)(xp1 + k0);
        const float4 b0 = *(const float4*)(wp0 + k0);
        const float4 b1 = *(const float4*)(wp1 + k0);
        __syncthreads();
        Asm[lk + 0][lr]      = a0.x; Asm[lk + 1][lr]      = a0.y;
        Asm[lk + 2][lr]      = a0.z; Asm[lk + 3][lr]      = a0.w;
        Asm[lk + 0][lr + 64] = a1.x; Asm[lk + 1][lr + 64] = a1.y;
        Asm[lk + 2][lr + 64] = a1.z; Asm[lk + 3][lr + 64] = a1.w;
        Bsm[lk + 0][lr]      = b0.x; Bsm[lk + 1][lr]      = b0.y;
        Bsm[lk + 2][lr]      = b0.z; Bsm[lk + 3][lr]      = b0.w;
        Bsm[lk + 0][lr + 64] = b1.x; Bsm[lk + 1][lr + 64] = b1.y;
        Bsm[lk + 2][lr + 64] = b1.z; Bsm[lk + 3][lr + 64] = b1.w;
        __syncthreads();
        #pragma unroll
        for (int kk = 0; kk < 16; ++kk) {
            float a[8], b[8];
            *(float4*)&a[0] = *(const float4*)&Asm[kk][ty * 8];
            *(float4*)&a[4] = *(const float4*)&Asm[kk][ty * 8 + 4];
            *(float4*)&b[0] = *(const float4*)&Bsm[kk][tx * 8];
            *(float4*)&b[4] = *(const float4*)&Bsm[kk][tx * 8 + 4];
            #pragma unroll
            for (int i = 0; i < 8; ++i)
                #pragma unroll
                for (int j = 0; j < 8; ++j)
                    acc[i][j] = fmaf(a[i], b[j], acc[i][j]);
        }
    }

    float bias[8];
    #pragma unroll
    for (int j = 0; j < 8; ++j) {
        const int col = n0 + tx * 8 + j;
        bias[j] = B1[col] + B2[col];
    }
    #pragma unroll
    for (int i = 0; i < 8; ++i) {
        const size_t off = (size_t)(m0 + ty * 8 + i) * D_LAT + n0 + tx * 8;
        float4 o0, o1;
        o0.x = acc[i][0] + bias[0]; o0.y = acc[i][1] + bias[1];
        o0.z = acc[i][2] + bias[2]; o0.w = acc[i][3] + bias[3];
        o1.x = acc[i][4] + bias[4]; o1.y = acc[i][5] + bias[5];
        o1.z = acc[i][6] + bias[6]; o1.w = acc[i][7] + bias[7];
        *(float4*)&PRE[off]     = o0;
        *(float4*)&PRE[off + 4] = o1;
    }
}

// ---------------------------------------------------------------------------
// Kernel: per-row top-16 via 2-round radix-select + short exact extraction.
// hist layout transposed: bin (12b) -> hist[(bin&15)*256 + (bin>>4)] so the
// phase-2 per-thread 16-bin sum reads bank t%32 (conflict-free).
// ---------------------------------------------------------------------------
__global__ __launch_bounds__(256) void topk_decode(
    float* __restrict__ LAT, const float* __restrict__ DT,
    const float* __restrict__ DW, float* __restrict__ REC, const int use_t)
{
    const int row = blockIdx.x;
    const int t = threadIdx.x;
    const int wv = t >> 6;
    const int ln = t & 63;
    float* prow = LAT + (size_t)row * D_LAT;

    __shared__ uint32_t hist[4096];     // 16KB, transposed layout
    __shared__ uint32_t h2[256];        // refinement histogram
    __shared__ uint32_t wsum[4];
    __shared__ uint32_t sh_b1, sh_cgt1, sh_prefix, sh_cgt2;
    __shared__ uint32_t s_wk[4];
    __shared__ int      s_wi[4];
    __shared__ float    topv[K_TOP];
    __shared__ int      topi[K_TOP];
    __shared__ uint32_t sh_cnt;

    // load row (coalesced: 1KB line per j)
    float v[16];
    #pragma unroll
    for (int j = 0; j < 16; ++j) v[j] = prow[t + 256 * j];

    // monotone key: larger key <=> larger float (finite data)
    uint32_t key[16];
    #pragma unroll
    for (int j = 0; j < 16; ++j) {
        const uint32_t b = __float_as_uint(v[j]);
        key[j] = (b & 0x80000000u) ? ~b : (b | 0x80000000u);
    }

    // phase 0: zero histograms
    #pragma unroll
    for (int i = 0; i < 16; ++i) hist[t + 256 * i] = 0;
    h2[t] = 0;
    if (t == 0) sh_cnt = 0;
    __syncthreads();

    // phase 1: 12-bit histogram (transposed addressing)
    #pragma unroll
    for (int j = 0; j < 16; ++j) {
        const uint32_t bin = key[j] >> 20;
        atomicAdd(&hist[(bin & 15u) * 256 + (bin >> 4)], 1u);
    }
    __syncthreads();

    // phase 2: block suffix-scan over 256 chunks of 16 bins; find rank-16 bin
    uint32_t s = 0;
    #pragma unroll
    for (int b = 0; b < 16; ++b) s += hist[b * 256 + t];
    uint32_t suf = s;                       // inclusive suffix within wave
    #pragma unroll
    for (int off = 1; off <= 32; off <<= 1) {
        const uint32_t o = __shfl_down(suf, off);
        if (ln + off < 64) suf += o;
    }
    if (ln == 0) wsum[wv] = suf;
    __syncthreads();
    uint32_t above = suf - s;               // lanes > ln, same wave
    for (int w2 = wv + 1; w2 < 4; ++w2) above += wsum[w2];
    if (above < K_TOP && above + s >= K_TOP) {   // unique owner chunk
        uint32_t acc = above;
        for (int b = 15; b >= 0; --b) {
            const uint32_t h = hist[b * 256 + t];
            if (acc + h >= K_TOP) { sh_b1 = (uint32_t)(t * 16 + b); sh_cgt1 = acc; break; }
            acc += h;
        }
    }
    __syncthreads();
    const uint32_t b1 = sh_b1;
    const uint32_t cgt1 = sh_cgt1;
    const uint32_t need1 = K_TOP - cgt1;

    // phase 3: refine on bits [19:12] among prefix-matched values
    #pragma unroll
    for (int j = 0; j < 16; ++j)
        if ((key[j] >> 20) == b1) atomicAdd(&h2[(key[j] >> 12) & 255u], 1u);
    __syncthreads();

    // phase 4: wave 0 suffix-scans h2 (4 bins/lane)
    if (wv == 0) {
        const int base = ln * 4;
        const uint32_t s2 = h2[base] + h2[base + 1] + h2[base + 2] + h2[base + 3];
        uint32_t suf2 = s2;
        #pragma unroll
        for (int off = 1; off <= 32; off <<= 1) {
            const uint32_t o = __shfl_down(suf2, off);
            if (ln + off < 64) suf2 += o;
        }
        const uint32_t E = suf2 - s2;       // bins in lanes > ln
        if (E < need1 && E + s2 >= need1) {
            uint32_t acc = E;
            for (int b = 3; b >= 0; --b) {
                const uint32_t h = h2[base + b];
                if (acc + h >= need1) {
                    sh_prefix = (b1 << 8) | (uint32_t)(base + b);
                    sh_cgt2 = cgt1 + acc;
                    break;
                }
                acc += h;
            }
        }
    }
    __syncthreads();
    const uint32_t prefix = sh_prefix;
    const uint32_t need_in = K_TOP - sh_cgt2;   // >= 1, uniform

    // phase 5: selection by 20-bit prefix; exact extraction for the boundary
    uint32_t sel = 0, candm = 0;
    #pragma unroll
    for (int j = 0; j < 16; ++j) {
        const uint32_t p = key[j] >> 12;
        if (p > prefix) sel |= 1u << j;
        else if (p == prefix) candm |= 1u << j;
    }
    for (uint32_t e = 0; e < need_in; ++e) {
        uint32_t bk = 0; int bi = 0x7FFFFFFF;
        #pragma unroll
        for (int j = 0; j < 16; ++j) {
            if ((candm >> j) & 1u) {
                const int lj = t + (j << 8);
                if (key[j] > bk || (key[j] == bk && lj < bi)) { bk = key[j]; bi = lj; }
            }
        }
        #pragma unroll
        for (int off = 32; off >= 1; off >>= 1) {
            const uint32_t ok = __shfl_xor(bk, off);
            const int      oi = __shfl_xor(bi, off);
            if (ok > bk || (ok == bk && oi < bi)) { bk = ok; bi = oi; }
        }
        if (ln == 0) { s_wk[wv] = bk; s_wi[wv] = bi; }
        __syncthreads();
        uint32_t fk = s_wk[0]; int fi = s_wi[0];
        for (int w2 = 1; w2 < 4; ++w2)
            if (s_wk[w2] > fk || (s_wk[w2] == fk && s_wi[w2] < fi)) { fk = s_wk[w2]; fi = s_wi[w2]; }
        if ((fi & 255) == t) {
            const int j = fi >> 8;
            candm &= ~(1u << j);
            sel   |=  (1u << j);
        }
        __syncthreads();
    }

    // phase 6: sparse latents write (relu on selected, zero elsewhere)
    #pragma unroll
    for (int j = 0; j < 16; ++j)
        prow[t + 256 * j] = ((sel >> j) & 1u) ? fmaxf(v[j], 0.f) : 0.f;

    // phase 7: compact selected (val, idx) -> LDS (exactly 16)
    #pragma unroll
    for (int j = 0; j < 16; ++j) {
        if ((sel >> j) & 1u) {
            const uint32_t slot = atomicAdd(&sh_cnt, 1u);
            topv[slot] = v[j];
            topi[slot] = t + (j << 8);
        }
    }
    __syncthreads();

    // phase 8: decode recon[row, d] = sum_k relu(val_k) * dec_w[d, l_k]
    float racc[4] = {0.f, 0.f, 0.f, 0.f};
    if (use_t) {
        #pragma unroll
        for (int k = 0; k < K_TOP; ++k) {
            const float val = fmaxf(topv[k], 0.f);
            const int   li  = topi[k];
            const float* wr = DT + (size_t)li * D_MOD + t;
            #pragma unroll
            for (int j = 0; j < 4; ++j)
                racc[j] = fmaf(val, wr[256 * j], racc[j]);
        }
    } else {
        #pragma unroll
        for (int k = 0; k < K_TOP; ++k) {
            const float val = fmaxf(topv[k], 0.f);
            const int   li  = topi[k];
            #pragma unroll
            for (int j = 0; j < 4; ++j)
                racc[j] = fmaf(val, DW[(size_t)(t + 256 * j) * D_LAT + li], racc[j]);
        }
    }
    float* rrow = REC + (size_t)row * D_MOD;
    #pragma unroll
    for (int j = 0; j < 4; ++j) rrow[t + 256 * j] = racc[j];
}

// ---------------------------------------------------------------------------
extern "C" void kernel_launch(void* const* d_in, const int* in_sizes, int n_in,
                              void* d_out, int out_size, void* d_ws, size_t ws_size,
                              hipStream_t stream)
{
    const float* x      = (const float*)d_in[0];
    const float* enc_w  = (const float*)d_in[1];
    const float* enc_b  = (const float*)d_in[2];
    const float* enc_b2 = (const float*)d_in[3];
    const float* dec_w  = (const float*)d_in[4];

    float* recon   = (float*)d_out;                    // [16384,1024]
    float* latents = recon + (size_t)N_ROWS * D_MOD;   // [16384,4096]

    char* ws = (char*)d_ws;
    // ws layout (bytes): decT fp32 [0,16M) | xh | xl | wh | wl (f16)
    float* decT = (float*)ws;
    f16_t* xh = (f16_t*)(ws + 16777216);
    f16_t* xl = (f16_t*)(ws + 50331648);
    f16_t* wh = (f16_t*)(ws + 83886080);
    f16_t* wl = (f16_t*)(ws + 92274688);
    const size_t need_fast = 100663296;
    const size_t need_t    = 16777216;
    const int has_t = (ws_size >= need_t) ? 1 : 0;
    const int fast  = (ws_size >= need_fast) ? 1 : 0;

    if (has_t)
        transpose_dec<<<dim3(D_LAT / 32, D_MOD / 32), 256, 0, stream>>>(dec_w, decT);

    if (fast) {
        split_f16<<<(N_ROWS * D_MOD / 4) / 256, 256, 0, stream>>>(x, xh, xl, N_ROWS * D_MOD / 4);
        split_f16<<<(D_LAT * D_MOD / 4) / 256, 256, 0, stream>>>(enc_w, wh, wl, D_LAT * D_MOD / 4);
        enc_gemm_f16<<<(N_ROWS / 128) * (D_LAT / 128), 256, 0, stream>>>(
            xh, xl, wh, wl, enc_b, enc_b2, latents);
    } else {
        enc_gemm_f32<<<dim3(D_LAT / 128, N_ROWS / 128), 256, 0, stream>>>(
            x, enc_w, enc_b, enc_b2, latents);
    }

    topk_decode<<<N_ROWS, 256, 0, stream>>>(latents, decT, dec_w, recon, has_t);
}

// Round 6
// 653.924 us; speedup vs baseline: 1.6018x; 1.6018x over previous
//
#include <hip/hip_runtime.h>
#include <cstdint>
#include <cstddef>

// Problem constants
#define N_ROWS  16384      // 4*4096 tokens
#define D_MOD   1024
#define D_LAT   4096
#define K_TOP   16

typedef _Float16 f16_t;
typedef _Float16 half8 __attribute__((ext_vector_type(8)));
typedef float f32x4 __attribute__((ext_vector_type(4)));

// ws layout element offsets (f16) — must match kernel_launch
#define XL_OFF  16777216u   // (50331648-16777216)/2
#define WL_OFF  4194304u    // (92274688-83886080)/2

// ---------------------------------------------------------------------------
// global_load_lds helper (16B per lane, LDS dest = wave-uniform base + lane*16)
// ---------------------------------------------------------------------------
__device__ __forceinline__ void gload_lds16(const void* g, void* l) {
    __builtin_amdgcn_global_load_lds(
        (const __attribute__((address_space(1))) void*)g,
        (__attribute__((address_space(3))) void*)l, 16, 0, 0);
}

// ---------------------------------------------------------------------------
// Kernel: split fp32 -> fp16 hi + fp16 lo*2^11  (exact Fast2Sum residual)
// ---------------------------------------------------------------------------
__global__ __launch_bounds__(256) void split_f16(
    const float* __restrict__ src, f16_t* __restrict__ hi,
    f16_t* __restrict__ lo, int n4)
{
    const int i = blockIdx.x * 256 + threadIdx.x;
    if (i >= n4) return;
    const float4 v = ((const float4*)src)[i];
    union { f16_t h[4]; ushort4 u; } ph, pl;
    ph.h[0] = (f16_t)v.x; ph.h[1] = (f16_t)v.y;
    ph.h[2] = (f16_t)v.z; ph.h[3] = (f16_t)v.w;
    pl.h[0] = (f16_t)((v.x - (float)ph.h[0]) * 2048.0f);
    pl.h[1] = (f16_t)((v.y - (float)ph.h[1]) * 2048.0f);
    pl.h[2] = (f16_t)((v.z - (float)ph.h[2]) * 2048.0f);
    pl.h[3] = (f16_t)((v.w - (float)ph.h[3]) * 2048.0f);
    ((ushort4*)hi)[i] = ph.u;
    ((ushort4*)lo)[i] = pl.u;
}

// ---------------------------------------------------------------------------
// Kernel: transpose dec_w [1024][4096] -> decT [4096][1024]
// ---------------------------------------------------------------------------
__global__ __launch_bounds__(256) void transpose_dec(
    const float* __restrict__ DW, float* __restrict__ DT)
{
    __shared__ float tile[32][33];
    const int l0 = blockIdx.x * 32;
    const int d0 = blockIdx.y * 32;
    const int tx = threadIdx.x & 31;
    const int ty = threadIdx.x >> 5;
    #pragma unroll
    for (int i = 0; i < 32; i += 8)
        tile[ty + i][tx] = DW[(size_t)(d0 + ty + i) * D_LAT + l0 + tx];
    __syncthreads();
    #pragma unroll
    for (int i = 0; i < 32; i += 8)
        DT[(size_t)(l0 + ty + i) * D_MOD + d0 + tx] = tile[tx][ty + i];
}

// ---------------------------------------------------------------------------
// Fused MFMA GEMM, BK=64 (round-3 structure) + register discipline.
// pre = xh*wh + (xh*wl + xl*wh)/2048 + bias.
// 128x128 tile, 4 waves (2x2), wave tile 64x64, frag 16x16x32 f16.
// 4 LDS buffers [128][64] f16 = 16KB each, 64KB total.
// LDS intensity 3 MFMA : 1 ds_read_b128 (ah shared by hh+hl; bh by hh+lh).
// Live frags kept to bh[4]+bl[4]+ah+al = 40 VGPR; __launch_bounds__(256,2)
// pins unified regs <= 256 (128 AGPR accs + <=128 VGPR) -> 2 waves/SIMD.
// Swizzle (chunk ^= row&7) via pre-swizzled global source, linear LDS dest.
// ---------------------------------------------------------------------------
__global__ __launch_bounds__(256, 2) void enc_gemm_f16(
    const f16_t* __restrict__ XH, const f16_t* __restrict__ WH,
    const float* __restrict__ B1, const float* __restrict__ B2,
    float* __restrict__ PRE)
{
    __shared__ char smem[65536];
    char* AsH = smem;
    char* AsL = smem + 16384;
    char* BsH = smem + 32768;
    char* BsL = smem + 49152;

    const int tid = threadIdx.x;
    const int w = tid >> 6;
    const int l = tid & 63;

    // XCD-bijective swizzle (4096 blocks % 8 == 0)
    const int bid = blockIdx.x;
    const int swz = (bid & 7) * 512 + (bid >> 3);
    const int bx = swz & 31;          // 32 n-blocks
    const int by = swz >> 5;          // 128 m-blocks
    const int m0 = by * 128, n0 = bx * 128;
    const int wm = w >> 1, wn = w & 1;

    f32x4 acc1[4][4], acc2[4][4];
    #pragma unroll
    for (int i = 0; i < 4; ++i)
        #pragma unroll
        for (int j = 0; j < 4; ++j) {
            acc1[i][j] = (f32x4)(0.0f);
            acc2[i][j] = (f32x4)(0.0f);
        }

    const int srow  = l >> 3;                 // 0..7 within 8-row chunk
    const int sclog = (l & 7) ^ srow;         // pre-swizzled logical chunk
    const size_t abase = (size_t)m0 * D_MOD;
    const size_t bbase = (size_t)n0 * D_MOD;
    const f16_t* XL = XH + XL_OFF;            // constant ws offsets
    const f16_t* WL = WH + WL_OFF;

    for (int k0 = 0; k0 < D_MOD; k0 += 64) {
        __syncthreads();   // all waves done reading LDS from previous step
        #pragma unroll
        for (int i = 0; i < 4; ++i) {
            const int cidx = i * 4 + w;                // 8-row chunk 0..15
            const size_t goff = (size_t)(cidx * 8 + srow) * D_MOD + k0 + sclog * 8;
            const int ldst = cidx * 1024;
            gload_lds16(XH + abase + goff, AsH + ldst);
            gload_lds16(XL + abase + goff, AsL + ldst);
            gload_lds16(WH + bbase + goff, BsH + ldst);
            gload_lds16(WL + bbase + goff, BsL + ldst);
        }
        __syncthreads();   // vmcnt(0) drained by compiler before barrier

        #pragma unroll
        for (int kk = 0; kk < 2; ++kk) {
            const int c = ((kk * 4) + (l >> 4)) ^ (l & 7);  // swizzled chunk
            half8 bh[4], bl[4];
            #pragma unroll
            for (int ni = 0; ni < 4; ++ni) {
                const int col = wn * 64 + ni * 16 + (l & 15);
                bh[ni] = *(const half8*)(BsH + col * 128 + c * 16);
                bl[ni] = *(const half8*)(BsL + col * 128 + c * 16);
            }
            #pragma unroll
            for (int mi = 0; mi < 4; ++mi) {
                const int row = wm * 64 + mi * 16 + (l & 15);
                const half8 ah = *(const half8*)(AsH + row * 128 + c * 16);
                #pragma unroll
                for (int ni = 0; ni < 4; ++ni)
                    acc1[mi][ni] = __builtin_amdgcn_mfma_f32_16x16x32_f16(
                        ah, bh[ni], acc1[mi][ni], 0, 0, 0);
                #pragma unroll
                for (int ni = 0; ni < 4; ++ni)
                    acc2[mi][ni] = __builtin_amdgcn_mfma_f32_16x16x32_f16(
                        ah, bl[ni], acc2[mi][ni], 0, 0, 0);
                const half8 al = *(const half8*)(AsL + row * 128 + c * 16);
                #pragma unroll
                for (int ni = 0; ni < 4; ++ni)
                    acc2[mi][ni] = __builtin_amdgcn_mfma_f32_16x16x32_f16(
                        al, bh[ni], acc2[mi][ni], 0, 0, 0);
            }
        }
    }

    // epilogue: pre = acc1 + acc2/2048 + bias
    const int lrow = (l >> 4) * 4;
    const int lcol = l & 15;
    #pragma unroll
    for (int ni = 0; ni < 4; ++ni) {
        const int col = n0 + wn * 64 + ni * 16 + lcol;
        const float bias = B1[col] + B2[col];
        #pragma unroll
        for (int mi = 0; mi < 4; ++mi) {
            const int row = m0 + wm * 64 + mi * 16 + lrow;
            #pragma unroll
            for (int j = 0; j < 4; ++j)
                PRE[(size_t)(row + j) * D_LAT + col] =
                    acc1[mi][ni][j] + acc2[mi][ni][j] * (1.0f / 2048.0f) + bias;
        }
    }
}

// ---------------------------------------------------------------------------
// Fallback: fp32 VALU GEMM (round-1, known-good)
// ---------------------------------------------------------------------------
__global__ __launch_bounds__(256) void enc_gemm_f32(
    const float* __restrict__ X, const float* __restrict__ W,
    const float* __restrict__ B1, const float* __restrict__ B2,
    float* __restrict__ PRE)
{
    __shared__ float Asm[16][128];
    __shared__ float Bsm[16][128];
    const int tid = threadIdx.x;
    const int m0 = blockIdx.y * 128;
    const int n0 = blockIdx.x * 128;
    const int tx = tid & 15;
    const int ty = tid >> 4;
    const int lr = tid >> 2;
    const int lk = (tid & 3) << 2;

    float acc[8][8];
    #pragma unroll
    for (int i = 0; i < 8; ++i)
        #pragma unroll
        for (int j = 0; j < 8; ++j) acc[i][j] = 0.f;

    const float* xp0 = X + (size_t)(m0 + lr) * D_MOD + lk;
    const float* xp1 = X + (size_t)(m0 + lr + 64) * D_MOD + lk;
    const float* wp0 = W + (size_t)(n0 + lr) * D_MOD + lk;
    const float* wp1 = W + (size_t)(n0 + lr + 64) * D_MOD + lk;

    for (int k0 = 0; k0 < D_MOD; k0 += 16) {
        const float4 a0 = *(const float4*)(xp0 + k0);
        const float4 a1 = *(const float4*)(xp1 + k0);
        const float4 b0 = *(const float4*)(wp0 + k0);
        const float4 b1 = *(const float4*)(wp1 + k0);
        __syncthreads();
        Asm[lk + 0][lr]      = a0.x; Asm[lk + 1][lr]      = a0.y;
        Asm[lk + 2][lr]      = a0.z; Asm[lk + 3][lr]      = a0.w;
        Asm[lk + 0][lr + 64] = a1.x; Asm[lk + 1][lr + 64] = a1.y;
        Asm[lk + 2][lr + 64] = a1.z; Asm[lk + 3][lr + 64] = a1.w;
        Bsm[lk + 0][lr]      = b0.x; Bsm[lk + 1][lr]      = b0.y;
        Bsm[lk + 2][lr]      = b0.z; Bsm[lk + 3][lr]      = b0.w;
        Bsm[lk + 0][lr + 64] = b1.x; Bsm[lk + 1][lr + 64] = b1.y;
        Bsm[lk + 2][lr + 64] = b1.z; Bsm[lk + 3][lr + 64] = b1.w;
        __syncthreads();
        #pragma unroll
        for (int kk = 0; kk < 16; ++kk) {
            float a[8], b[8];
            *(float4*)&a[0] = *(const float4*)&Asm[kk][ty * 8];
            *(float4*)&a[4] = *(const float4*)&Asm[kk][ty * 8 + 4];
            *(float4*)&b[0] = *(const float4*)&Bsm[kk][tx * 8];
            *(float4*)&b[4] = *(const float4*)&Bsm[kk][tx * 8 + 4];
            #pragma unroll
            for (int i = 0; i < 8; ++i)
                #pragma unroll
                for (int j = 0; j < 8; ++j)
                    acc[i][j] = fmaf(a[i], b[j], acc[i][j]);
        }
    }

    float bias[8];
    #pragma unroll
    for (int j = 0; j < 8; ++j) {
        const int col = n0 + tx * 8 + j;
        bias[j] = B1[col] + B2[col];
    }
    #pragma unroll
    for (int i = 0; i < 8; ++i) {
        const size_t off = (size_t)(m0 + ty * 8 + i) * D_LAT + n0 + tx * 8;
        float4 o0, o1;
        o0.x = acc[i][0] + bias[0]; o0.y = acc[i][1] + bias[1];
        o0.z = acc[i][2] + bias[2]; o0.w = acc[i][3] + bias[3];
        o1.x = acc[i][4] + bias[4]; o1.y = acc[i][5] + bias[5];
        o1.z = acc[i][6] + bias[6]; o1.w = acc[i][7] + bias[7];
        *(float4*)&PRE[off]     = o0;
        *(float4*)&PRE[off + 4] = o1;
    }
}

// ---------------------------------------------------------------------------
// Kernel: per-row top-16 via 2-round radix-select + short exact extraction.
// (round-4 version, measured good)
// ---------------------------------------------------------------------------
__global__ __launch_bounds__(256) void topk_decode(
    float* __restrict__ LAT, const float* __restrict__ DT,
    const float* __restrict__ DW, float* __restrict__ REC, const int use_t)
{
    const int row = blockIdx.x;
    const int t = threadIdx.x;
    const int wv = t >> 6;
    const int ln = t & 63;
    float* prow = LAT + (size_t)row * D_LAT;

    __shared__ uint32_t hist[4096];     // 16KB, transposed layout
    __shared__ uint32_t h2[256];        // refinement histogram
    __shared__ uint32_t wsum[4];
    __shared__ uint32_t sh_b1, sh_cgt1, sh_prefix, sh_cgt2;
    __shared__ uint32_t s_wk[4];
    __shared__ int      s_wi[4];
    __shared__ float    topv[K_TOP];
    __shared__ int      topi[K_TOP];
    __shared__ uint32_t sh_cnt;

    // load row (coalesced: 1KB line per j)
    float v[16];
    #pragma unroll
    for (int j = 0; j < 16; ++j) v[j] = prow[t + 256 * j];

    // monotone key: larger key <=> larger float (finite data)
    uint32_t key[16];
    #pragma unroll
    for (int j = 0; j < 16; ++j) {
        const uint32_t b = __float_as_uint(v[j]);
        key[j] = (b & 0x80000000u) ? ~b : (b | 0x80000000u);
    }

    // phase 0: zero histograms
    #pragma unroll
    for (int i = 0; i < 16; ++i) hist[t + 256 * i] = 0;
    h2[t] = 0;
    if (t == 0) sh_cnt = 0;
    __syncthreads();

    // phase 1: 12-bit histogram (transposed addressing)
    #pragma unroll
    for (int j = 0; j < 16; ++j) {
        const uint32_t bin = key[j] >> 20;
        atomicAdd(&hist[(bin & 15u) * 256 + (bin >> 4)], 1u);
    }
    __syncthreads();

    // phase 2: block suffix-scan over 256 chunks of 16 bins; find rank-16 bin
    uint32_t s = 0;
    #pragma unroll
    for (int b = 0; b < 16; ++b) s += hist[b * 256 + t];
    uint32_t suf = s;                       // inclusive suffix within wave
    #pragma unroll
    for (int off = 1; off <= 32; off <<= 1) {
        const uint32_t o = __shfl_down(suf, off);
        if (ln + off < 64) suf += o;
    }
    if (ln == 0) wsum[wv] = suf;
    __syncthreads();
    uint32_t above = suf - s;               // lanes > ln, same wave
    for (int w2 = wv + 1; w2 < 4; ++w2) above += wsum[w2];
    if (above < K_TOP && above + s >= K_TOP) {   // unique owner chunk
        uint32_t acc = above;
        for (int b = 15; b >= 0; --b) {
            const uint32_t h = hist[b * 256 + t];
            if (acc + h >= K_TOP) { sh_b1 = (uint32_t)(t * 16 + b); sh_cgt1 = acc; break; }
            acc += h;
        }
    }
    __syncthreads();
    const uint32_t b1 = sh_b1;
    const uint32_t cgt1 = sh_cgt1;
    const uint32_t need1 = K_TOP - cgt1;

    // phase 3: refine on bits [19:12] among prefix-matched values
    #pragma unroll
    for (int j = 0; j < 16; ++j)
        if ((key[j] >> 20) == b1) atomicAdd(&h2[(key[j] >> 12) & 255u], 1u);
    __syncthreads();

    // phase 4: wave 0 suffix-scans h2 (4 bins/lane)
    if (wv == 0) {
        const int base = ln * 4;
        const uint32_t s2 = h2[base] + h2[base + 1] + h2[base + 2] + h2[base + 3];
        uint32_t suf2 = s2;
        #pragma unroll
        for (int off = 1; off <= 32; off <<= 1) {
            const uint32_t o = __shfl_down(suf2, off);
            if (ln + off < 64) suf2 += o;
        }
        const uint32_t E = suf2 - s2;       // bins in lanes > ln
        if (E < need1 && E + s2 >= need1) {
            uint32_t acc = E;
            for (int b = 3; b >= 0; --b) {
                const uint32_t h = h2[base + b];
                if (acc + h >= need1) {
                    sh_prefix = (b1 << 8) | (uint32_t)(base + b);
                    sh_cgt2 = cgt1 + acc;
                    break;
                }
                acc += h;
            }
        }
    }
    __syncthreads();
    const uint32_t prefix = sh_prefix;
    const uint32_t need_in = K_TOP - sh_cgt2;   // >= 1, uniform

    // phase 5: selection by 20-bit prefix; exact extraction for the boundary
    uint32_t sel = 0, candm = 0;
    #pragma unroll
    for (int j = 0; j < 16; ++j) {
        const uint32_t p = key[j] >> 12;
        if (p > prefix) sel |= 1u << j;
        else if (p == prefix) candm |= 1u << j;
    }
    for (uint32_t e = 0; e < need_in; ++e) {
        uint32_t bk = 0; int bi = 0x7FFFFFFF;
        #pragma unroll
        for (int j = 0; j < 16; ++j) {
            if ((candm >> j) & 1u) {
                const int lj = t + (j << 8);
                if (key[j] > bk || (key[j] == bk && lj < bi)) { bk = key[j]; bi = lj; }
            }
        }
        #pragma unroll
        for (int off = 32; off >= 1; off >>= 1) {
            const uint32_t ok = __shfl_xor(bk, off);
            const int      oi = __shfl_xor(bi, off);
            if (ok > bk || (ok == bk && oi < bi)) { bk = ok; bi = oi; }
        }
        if (ln == 0) { s_wk[wv] = bk; s_wi[wv] = bi; }
        __syncthreads();
        uint32_t fk = s_wk[0]; int fi = s_wi[0];
        for (int w2 = 1; w2 < 4; ++w2)
            if (s_wk[w2] > fk || (s_wk[w2] == fk && s_wi[w2] < fi)) { fk = s_wk[w2]; fi = s_wi[w2]; }
        if ((fi & 255) == t) {
            const int j = fi >> 8;
            candm &= ~(1u << j);
            sel   |=  (1u << j);
        }
        __syncthreads();
    }

    // phase 6: sparse latents write (relu on selected, zero elsewhere)
    #pragma unroll
    for (int j = 0; j < 16; ++j)
        prow[t + 256 * j] = ((sel >> j) & 1u) ? fmaxf(v[j], 0.f) : 0.f;

    // phase 7: compact selected (val, idx) -> LDS (exactly 16)
    #pragma unroll
    for (int j = 0; j < 16; ++j) {
        if ((sel >> j) & 1u) {
            const uint32_t slot = atomicAdd(&sh_cnt, 1u);
            topv[slot] = v[j];
            topi[slot] = t + (j << 8);
        }
    }
    __syncthreads();

    // phase 8: decode recon[row, d] = sum_k relu(val_k) * dec_w[d, l_k]
    float racc[4] = {0.f, 0.f, 0.f, 0.f};
    if (use_t) {
        #pragma unroll
        for (int k = 0; k < K_TOP; ++k) {
            const float val = fmaxf(topv[k], 0.f);
            const int   li  = topi[k];
            const float* wr = DT + (size_t)li * D_MOD + t;
            #pragma unroll
            for (int j = 0; j < 4; ++j)
                racc[j] = fmaf(val, wr[256 * j], racc[j]);
        }
    } else {
        #pragma unroll
        for (int k = 0; k < K_TOP; ++k) {
            const float val = fmaxf(topv[k], 0.f);
            const int   li  = topi[k];
            #pragma unroll
            for (int j = 0; j < 4; ++j)
                racc[j] = fmaf(val, DW[(size_t)(t + 256 * j) * D_LAT + li], racc[j]);
        }
    }
    float* rrow = REC + (size_t)row * D_MOD;
    #pragma unroll
    for (int j = 0; j < 4; ++j) rrow[t + 256 * j] = racc[j];
}

// ---------------------------------------------------------------------------
extern "C" void kernel_launch(void* const* d_in, const int* in_sizes, int n_in,
                              void* d_out, int out_size, void* d_ws, size_t ws_size,
                              hipStream_t stream)
{
    const float* x      = (const float*)d_in[0];
    const float* enc_w  = (const float*)d_in[1];
    const float* enc_b  = (const float*)d_in[2];
    const float* enc_b2 = (const float*)d_in[3];
    const float* dec_w  = (const float*)d_in[4];

    float* recon   = (float*)d_out;                    // [16384,1024]
    float* latents = recon + (size_t)N_ROWS * D_MOD;   // [16384,4096]

    char* ws = (char*)d_ws;
    // ws layout (bytes): decT fp32 [0,16M) | xh | xl | wh | wl (f16)
    float* decT = (float*)ws;
    f16_t* xh = (f16_t*)(ws + 16777216);
    f16_t* xl = (f16_t*)(ws + 50331648);   // = xh + XL_OFF elems
    f16_t* wh = (f16_t*)(ws + 83886080);
    f16_t* wl = (f16_t*)(ws + 92274688);   // = wh + WL_OFF elems
    const size_t need_fast = 100663296;
    const size_t need_t    = 16777216;
    const int has_t = (ws_size >= need_t) ? 1 : 0;
    const int fast  = (ws_size >= need_fast) ? 1 : 0;

    if (has_t)
        transpose_dec<<<dim3(D_LAT / 32, D_MOD / 32), 256, 0, stream>>>(dec_w, decT);

    if (fast) {
        split_f16<<<(N_ROWS * D_MOD / 4) / 256, 256, 0, stream>>>(x, xh, xl, N_ROWS * D_MOD / 4);
        split_f16<<<(D_LAT * D_MOD / 4) / 256, 256, 0, stream>>>(enc_w, wh, wl, D_LAT * D_MOD / 4);
        enc_gemm_f16<<<(N_ROWS / 128) * (D_LAT / 128), 256, 0, stream>>>(
            xh, wh, enc_b, enc_b2, latents);
    } else {
        enc_gemm_f32<<<dim3(D_LAT / 128, N_ROWS / 128), 256, 0, stream>>>(
            x, enc_w, enc_b, enc_b2, latents);
    }

    topk_decode<<<N_ROWS, 256, 0, stream>>>(latents, decT, dec_w, recon, has_t);
}